// Round 3
// baseline (438.790 us; speedup 1.0000x reference)
//
#include <hip/hip_runtime.h>

#define C_LAB 24
#define EDIM 16
#define PPIX (768 * 768)
#define NB 4

// ws layout in 4-byte words:
// [0,96)        counts (int)
// [96,1632)     sums (float)    N*C*E
// [1632,3168)   means (float)   N*C*E
// [3168,3172)   reg per n
// [3172,3176)   triplet per n
// [3176,3180)   varsum per n
#define WS_WORDS 3180

__global__ __launch_bounds__(256) void k_zero(int* ws) {
    for (int i = threadIdx.x; i < WS_WORDS; i += 256) ws[i] = 0;
}

__global__ __launch_bounds__(256) void k_accum(const float* __restrict__ in,
                                               const int* __restrict__ tgt,
                                               float* __restrict__ sums,
                                               int* __restrict__ counts) {
    const int n = blockIdx.y;
    const int tid = threadIdx.x;
    __shared__ float ls[C_LAB][EDIM + 1];   // pad to 17 to spread banks
    __shared__ int lc[C_LAB];
    for (int i = tid; i < C_LAB * (EDIM + 1); i += 256) (&ls[0][0])[i] = 0.f;
    if (tid < C_LAB) lc[tid] = 0;
    __syncthreads();

    const size_t p0 = (size_t)(blockIdx.x * 256 + tid) * 4;
    const float* bp = in + (size_t)n * EDIM * PPIX + p0;
    int4 lab = *reinterpret_cast<const int4*>(tgt + (size_t)n * PPIX + p0);
    float4 x[EDIM];
#pragma unroll
    for (int e = 0; e < EDIM; ++e)
        x[e] = *reinterpret_cast<const float4*>(bp + (size_t)e * PPIX);

    int labs[4] = {lab.x, lab.y, lab.z, lab.w};
#pragma unroll
    for (int j = 0; j < 4; ++j) {
        const int c = labs[j];
        atomicAdd(&lc[c], 1);
#pragma unroll
        for (int e = 0; e < EDIM; ++e)
            atomicAdd(&ls[c][e], reinterpret_cast<const float*>(&x[e])[j]);
    }
    __syncthreads();

    for (int i = tid; i < C_LAB * EDIM; i += 256) {
        const int c = i >> 4, e = i & 15;
        atomicAdd(&sums[((size_t)n * C_LAB + c) * EDIM + e], ls[c][e]);
    }
    if (tid < C_LAB) atomicAdd(&counts[n * C_LAB + tid], lc[tid]);
}

__global__ __launch_bounds__(128) void k_means(const float* __restrict__ sums,
                                               const int* __restrict__ counts,
                                               float* __restrict__ means,
                                               float* __restrict__ regv) {
    const int t = threadIdx.x;
    if (t >= NB * C_LAB) return;
    const int n = t / C_LAB;
    const float inv = 1.f / (float)counts[t];
    float s2 = 0.f;
#pragma unroll
    for (int e = 0; e < EDIM; ++e) {
        float m = sums[t * EDIM + e] * inv;
        means[t * EDIM + e] = m;
        s2 += m * m;
    }
    float d = sqrtf(s2) - 1.f;
    atomicAdd(&regv[n], d * d);
}

__global__ __launch_bounds__(256) void k_triplet(const float* __restrict__ means,
                                                 const int* __restrict__ eattr,
                                                 const int* __restrict__ erep,
                                                 float* __restrict__ tripv) {
    const int n = blockIdx.x;
    const int tid = threadIdx.x;
    __shared__ float cm[C_LAB][EDIM];
    __shared__ float dA[200], dR[200];
    __shared__ int a0[200], a1[200], r0[200], r1[200];
    for (int i = tid; i < C_LAB * EDIM; i += 256)
        (&cm[0][0])[i] = means[n * C_LAB * EDIM + i];
    __syncthreads();
    if (tid < 200) {
        int i0 = eattr[n * 400 + tid], i1 = eattr[n * 400 + 200 + tid];
        a0[tid] = i0; a1[tid] = i1;
        float s = 0.f;
#pragma unroll
        for (int e = 0; e < EDIM; ++e) {
            float d = cm[i0][e] - cm[i1][e] + 1e-6f;
            s += d * d;
        }
        dA[tid] = s;
        i0 = erep[n * 400 + tid]; i1 = erep[n * 400 + 200 + tid];
        r0[tid] = i0; r1[tid] = i1;
        s = 0.f;
#pragma unroll
        for (int e = 0; e < EDIM; ++e) {
            float d = cm[i0][e] - cm[i1][e] + 1e-6f;
            s += d * d;
        }
        dR[tid] = s;
    }
    __syncthreads();

    float sum = 0.f;
    int cnt = 0;
    for (int idx = tid; idx < 200 * 200; idx += 256) {
        const int a = idx / 200;
        const int r = idx - a * 200;
        const int m = (a0[a] == r0[r]) + (a0[a] == r1[r]) +
                      (a1[a] == r0[r]) + (a1[a] == r1[r]);
        const float t = 0.5f * (dA[a] - dR[r]) + 0.01f;
        if (m == 1 && t > 0.f) { sum += t; cnt++; }
    }
    for (int o = 32; o; o >>= 1) {
        sum += __shfl_down(sum, o, 64);
        cnt += __shfl_down(cnt, o, 64);
    }
    __shared__ float rs[4];
    __shared__ int rc[4];
    if ((tid & 63) == 0) { rs[tid >> 6] = sum; rc[tid >> 6] = cnt; }
    __syncthreads();
    if (tid == 0) {
        float S = rs[0] + rs[1] + rs[2] + rs[3];
        int Cn = rc[0] + rc[1] + rc[2] + rc[3];
        tripv[n] = (Cn > 0) ? S / (float)Cn : 0.f;
    }
}

__global__ __launch_bounds__(256) void k_var(const float* __restrict__ in,
                                             const int* __restrict__ tgt,
                                             const float* __restrict__ means,
                                             const int* __restrict__ counts,
                                             float* __restrict__ varv) {
    const int n = blockIdx.y;
    const int tid = threadIdx.x;
    __shared__ float lm[C_LAB][EDIM + 1];
    __shared__ float licnt[C_LAB];
    for (int i = tid; i < C_LAB * EDIM; i += 256) {
        const int c = i >> 4, e = i & 15;
        lm[c][e] = means[(size_t)n * C_LAB * EDIM + i];
    }
    if (tid < C_LAB) licnt[tid] = 1.f / (float)counts[n * C_LAB + tid];
    __syncthreads();

    const size_t p0 = (size_t)(blockIdx.x * 256 + tid) * 4;
    const float* bp = in + (size_t)n * EDIM * PPIX + p0;
    int4 lab = *reinterpret_cast<const int4*>(tgt + (size_t)n * PPIX + p0);
    float4 x[EDIM];
#pragma unroll
    for (int e = 0; e < EDIM; ++e)
        x[e] = *reinterpret_cast<const float4*>(bp + (size_t)e * PPIX);

    int labs[4] = {lab.x, lab.y, lab.z, lab.w};
    float acc = 0.f;
#pragma unroll
    for (int j = 0; j < 4; ++j) {
        const int c = labs[j];
        float d2 = 0.f;
#pragma unroll
        for (int e = 0; e < EDIM; ++e) {
            float d = reinterpret_cast<const float*>(&x[e])[j] - lm[c][e];
            d2 += d * d;
        }
        float h = fmaxf(sqrtf(d2) - 0.5f, 0.f);
        acc += h * h * licnt[c];
    }
    for (int o = 32; o; o >>= 1) acc += __shfl_down(acc, o, 64);
    __shared__ float rs[4];
    if ((tid & 63) == 0) rs[tid >> 6] = acc;
    __syncthreads();
    if (tid == 0) atomicAdd(&varv[n], rs[0] + rs[1] + rs[2] + rs[3]);
}

__global__ void k_final(const float* __restrict__ varv,
                        const float* __restrict__ tripv,
                        const float* __restrict__ regv,
                        float* __restrict__ out) {
    float s = 0.f;
#pragma unroll
    for (int n = 0; n < NB; ++n)
        s += varv[n] / (float)C_LAB + tripv[n] + regv[n] / (float)C_LAB;
    out[0] = s / (float)(NB * NB);
}

extern "C" void kernel_launch(void* const* d_in, const int* in_sizes, int n_in,
                              void* d_out, int out_size, void* d_ws, size_t ws_size,
                              hipStream_t stream) {
    const float* input = (const float*)d_in[0];
    const int* target = (const int*)d_in[1];
    const int* eattr = (const int*)d_in[2];
    const int* erep = (const int*)d_in[3];
    float* out = (float*)d_out;

    int* counts = (int*)d_ws;
    float* wsf = (float*)d_ws;
    float* sums = wsf + 96;
    float* means = wsf + 1632;
    float* regv = wsf + 3168;
    float* tripv = wsf + 3172;
    float* varv = wsf + 3176;

    k_zero<<<1, 256, 0, stream>>>((int*)d_ws);

    dim3 grid(PPIX / (256 * 4), NB);  // 576 x 4
    k_accum<<<grid, 256, 0, stream>>>(input, target, sums, counts);
    k_means<<<1, 128, 0, stream>>>(sums, counts, means, regv);
    k_triplet<<<NB, 256, 0, stream>>>(means, eattr, erep, tripv);
    k_var<<<grid, 256, 0, stream>>>(input, target, means, counts, varv);
    k_final<<<1, 1, 0, stream>>>(varv, tripv, regv, out);
}

// Round 4
// 429.638 us; speedup vs baseline: 1.0213x; 1.0213x over previous
//
#include <hip/hip_runtime.h>

#define C_LAB 24
#define EDIM 16
#define PPIX (768 * 768)
#define NB 4

// ws layout in 4-byte words:
// [0,96)        counts (int)
// [96,1632)     sums (float)    N*C*E
// [1632,3168)   means (float)   N*C*E
// [3168,3172)   reg per n
// [3172,3176)   triplet per n
// [3176,3180)   varsum per n
#define WS_WORDS 3180

__global__ __launch_bounds__(256) void k_zero(int* ws) {
    for (int i = threadIdx.x; i < WS_WORDS; i += 256) ws[i] = 0;
}

// One channel value live at a time: load float4 of channel e, scatter its 4
// lane-values into the LDS histogram immediately. Live set ~12 VGPRs (was:
// float4 x[16] = 68+ live -> scratch spill at VGPR_Count=48, ~210us).
__global__ __launch_bounds__(256) void k_accum(const float* __restrict__ in,
                                               const int* __restrict__ tgt,
                                               float* __restrict__ sums,
                                               int* __restrict__ counts) {
    const int n = blockIdx.y;
    const int tid = threadIdx.x;
    __shared__ float ls[C_LAB][EDIM + 1];   // pad to 17 to spread banks
    __shared__ int lc[C_LAB];
    for (int i = tid; i < C_LAB * (EDIM + 1); i += 256) (&ls[0][0])[i] = 0.f;
    if (tid < C_LAB) lc[tid] = 0;
    __syncthreads();

    const size_t p0 = (size_t)(blockIdx.x * 256 + tid) * 4;
    const float* bp = in + (size_t)n * EDIM * PPIX + p0;
    const int4 lab = *reinterpret_cast<const int4*>(tgt + (size_t)n * PPIX + p0);

    atomicAdd(&lc[lab.x], 1);
    atomicAdd(&lc[lab.y], 1);
    atomicAdd(&lc[lab.z], 1);
    atomicAdd(&lc[lab.w], 1);

#pragma unroll
    for (int e = 0; e < EDIM; ++e) {
        const float4 xe = *reinterpret_cast<const float4*>(bp + (size_t)e * PPIX);
        atomicAdd(&ls[lab.x][e], xe.x);
        atomicAdd(&ls[lab.y][e], xe.y);
        atomicAdd(&ls[lab.z][e], xe.z);
        atomicAdd(&ls[lab.w][e], xe.w);
    }
    __syncthreads();

    for (int i = tid; i < C_LAB * EDIM; i += 256) {
        const int c = i >> 4, e = i & 15;
        atomicAdd(&sums[((size_t)n * C_LAB + c) * EDIM + e], ls[c][e]);
    }
    if (tid < C_LAB) atomicAdd(&counts[n * C_LAB + tid], lc[tid]);
}

__global__ __launch_bounds__(128) void k_means(const float* __restrict__ sums,
                                               const int* __restrict__ counts,
                                               float* __restrict__ means,
                                               float* __restrict__ regv) {
    const int t = threadIdx.x;
    if (t >= NB * C_LAB) return;
    const int n = t / C_LAB;
    const float inv = 1.f / (float)counts[t];
    float s2 = 0.f;
#pragma unroll
    for (int e = 0; e < EDIM; ++e) {
        float m = sums[t * EDIM + e] * inv;
        means[t * EDIM + e] = m;
        s2 += m * m;
    }
    float d = sqrtf(s2) - 1.f;
    atomicAdd(&regv[n], d * d);
}

__global__ __launch_bounds__(256) void k_triplet(const float* __restrict__ means,
                                                 const int* __restrict__ eattr,
                                                 const int* __restrict__ erep,
                                                 float* __restrict__ tripv) {
    const int n = blockIdx.x;
    const int tid = threadIdx.x;
    __shared__ float cm[C_LAB][EDIM];
    __shared__ float dA[200], dR[200];
    __shared__ int a0[200], a1[200], r0[200], r1[200];
    for (int i = tid; i < C_LAB * EDIM; i += 256)
        (&cm[0][0])[i] = means[n * C_LAB * EDIM + i];
    __syncthreads();
    if (tid < 200) {
        int i0 = eattr[n * 400 + tid], i1 = eattr[n * 400 + 200 + tid];
        a0[tid] = i0; a1[tid] = i1;
        float s = 0.f;
#pragma unroll
        for (int e = 0; e < EDIM; ++e) {
            float d = cm[i0][e] - cm[i1][e] + 1e-6f;
            s += d * d;
        }
        dA[tid] = s;
        i0 = erep[n * 400 + tid]; i1 = erep[n * 400 + 200 + tid];
        r0[tid] = i0; r1[tid] = i1;
        s = 0.f;
#pragma unroll
        for (int e = 0; e < EDIM; ++e) {
            float d = cm[i0][e] - cm[i1][e] + 1e-6f;
            s += d * d;
        }
        dR[tid] = s;
    }
    __syncthreads();

    float sum = 0.f;
    int cnt = 0;
    for (int idx = tid; idx < 200 * 200; idx += 256) {
        const int a = idx / 200;
        const int r = idx - a * 200;
        const int m = (a0[a] == r0[r]) + (a0[a] == r1[r]) +
                      (a1[a] == r0[r]) + (a1[a] == r1[r]);
        const float t = 0.5f * (dA[a] - dR[r]) + 0.01f;
        if (m == 1 && t > 0.f) { sum += t; cnt++; }
    }
    for (int o = 32; o; o >>= 1) {
        sum += __shfl_down(sum, o, 64);
        cnt += __shfl_down(cnt, o, 64);
    }
    __shared__ float rs[4];
    __shared__ int rc[4];
    if ((tid & 63) == 0) { rs[tid >> 6] = sum; rc[tid >> 6] = cnt; }
    __syncthreads();
    if (tid == 0) {
        float S = rs[0] + rs[1] + rs[2] + rs[3];
        int Cn = rc[0] + rc[1] + rc[2] + rc[3];
        tripv[n] = (Cn > 0) ? S / (float)Cn : 0.f;
    }
}

// Accumulate per-pixel partial d2 across channels; one float4 live at a time.
__global__ __launch_bounds__(256) void k_var(const float* __restrict__ in,
                                             const int* __restrict__ tgt,
                                             const float* __restrict__ means,
                                             const int* __restrict__ counts,
                                             float* __restrict__ varv) {
    const int n = blockIdx.y;
    const int tid = threadIdx.x;
    __shared__ float lm[C_LAB][EDIM + 1];
    __shared__ float licnt[C_LAB];
    for (int i = tid; i < C_LAB * EDIM; i += 256) {
        const int c = i >> 4, e = i & 15;
        lm[c][e] = means[(size_t)n * C_LAB * EDIM + i];
    }
    if (tid < C_LAB) licnt[tid] = 1.f / (float)counts[n * C_LAB + tid];
    __syncthreads();

    const size_t p0 = (size_t)(blockIdx.x * 256 + tid) * 4;
    const float* bp = in + (size_t)n * EDIM * PPIX + p0;
    const int4 lab = *reinterpret_cast<const int4*>(tgt + (size_t)n * PPIX + p0);

    float d0 = 0.f, d1 = 0.f, d2 = 0.f, d3 = 0.f;
#pragma unroll
    for (int e = 0; e < EDIM; ++e) {
        const float4 xe = *reinterpret_cast<const float4*>(bp + (size_t)e * PPIX);
        float t0 = xe.x - lm[lab.x][e];
        float t1 = xe.y - lm[lab.y][e];
        float t2 = xe.z - lm[lab.z][e];
        float t3 = xe.w - lm[lab.w][e];
        d0 += t0 * t0;
        d1 += t1 * t1;
        d2 += t2 * t2;
        d3 += t3 * t3;
    }

    float h0 = fmaxf(sqrtf(d0) - 0.5f, 0.f);
    float h1 = fmaxf(sqrtf(d1) - 0.5f, 0.f);
    float h2 = fmaxf(sqrtf(d2) - 0.5f, 0.f);
    float h3 = fmaxf(sqrtf(d3) - 0.5f, 0.f);
    float acc = h0 * h0 * licnt[lab.x] + h1 * h1 * licnt[lab.y] +
                h2 * h2 * licnt[lab.z] + h3 * h3 * licnt[lab.w];

    for (int o = 32; o; o >>= 1) acc += __shfl_down(acc, o, 64);
    __shared__ float rs[4];
    if ((tid & 63) == 0) rs[tid >> 6] = acc;
    __syncthreads();
    if (tid == 0) atomicAdd(&varv[n], rs[0] + rs[1] + rs[2] + rs[3]);
}

__global__ void k_final(const float* __restrict__ varv,
                        const float* __restrict__ tripv,
                        const float* __restrict__ regv,
                        float* __restrict__ out) {
    float s = 0.f;
#pragma unroll
    for (int n = 0; n < NB; ++n)
        s += varv[n] / (float)C_LAB + tripv[n] + regv[n] / (float)C_LAB;
    out[0] = s / (float)(NB * NB);
}

extern "C" void kernel_launch(void* const* d_in, const int* in_sizes, int n_in,
                              void* d_out, int out_size, void* d_ws, size_t ws_size,
                              hipStream_t stream) {
    const float* input = (const float*)d_in[0];
    const int* target = (const int*)d_in[1];
    const int* eattr = (const int*)d_in[2];
    const int* erep = (const int*)d_in[3];
    float* out = (float*)d_out;

    int* counts = (int*)d_ws;
    float* wsf = (float*)d_ws;
    float* sums = wsf + 96;
    float* means = wsf + 1632;
    float* regv = wsf + 3168;
    float* tripv = wsf + 3172;
    float* varv = wsf + 3176;

    k_zero<<<1, 256, 0, stream>>>((int*)d_ws);

    dim3 grid(PPIX / (256 * 4), NB);  // 576 x 4
    k_accum<<<grid, 256, 0, stream>>>(input, target, sums, counts);
    k_means<<<1, 128, 0, stream>>>(sums, counts, means, regv);
    k_triplet<<<NB, 256, 0, stream>>>(means, eattr, erep, tripv);
    k_var<<<grid, 256, 0, stream>>>(input, target, means, counts, varv);
    k_final<<<1, 1, 0, stream>>>(varv, tripv, regv, out);
}